// Round 5
// baseline (403.809 us; speedup 1.0000x reference)
//
#include <hip/hip_runtime.h>
#include <hip/hip_bf16.h>

#define DIM   1024
#define NVEC  128
#define BROWS 32768

typedef short s16x8 __attribute__((ext_vector_type(8)));
typedef float f32x4 __attribute__((ext_vector_type(4)));

__device__ __forceinline__ unsigned short f2bf(float f) {
    union { float f; unsigned int u; } c; c.f = f;
    unsigned int u = c.u;
    u += 0x7fffu + ((u >> 16) & 1u);   // round-to-nearest-even
    return (unsigned short)(u >> 16);
}

// ---------------------------------------------------------------------------
// K1: per-column normalize v AND raw Gram row (rescale trick):
//   G[i][j] = <v_i_raw, v_j_raw> * rn_i * rn_j  (scaling applied in k_tinv)
// ---------------------------------------------------------------------------
__global__ __launch_bounds__(256) void k_normgram(const float* __restrict__ v,
                                                  float* __restrict__ VnT,
                                                  unsigned short* __restrict__ VnT16,
                                                  float* __restrict__ rn_out,
                                                  float* __restrict__ G0) {
    int i = blockIdx.x, t = threadIdx.x;
    __shared__ float col[DIM];
    __shared__ float red[4];
    __shared__ float part[256];
    float c4[4]; float ss = 0.f;
#pragma unroll
    for (int u = 0; u < 4; ++u) {
        int d = t + u * 256;
        float val = v[d * NVEC + i];
        c4[u] = val; col[d] = val; ss += val * val;
    }
#pragma unroll
    for (int o = 32; o > 0; o >>= 1) ss += __shfl_down(ss, o, 64);
    if ((t & 63) == 0) red[t >> 6] = ss;
    __syncthreads();
    float rn = rsqrtf(red[0] + red[1] + red[2] + red[3]);
    if (t == 0) rn_out[i] = rn;
#pragma unroll
    for (int u = 0; u < 4; ++u) {
        int d = t + u * 256;
        float val = c4[u] * rn;
        VnT[i * DIM + d]   = val;
        VnT16[i * DIM + d] = f2bf(val);
    }
    // raw Gram row: thread t -> j = t&127, d-half = t>>7
    int j = t & 127, half = t >> 7;
    const float* vp = v + (size_t)(half * 512) * NVEC + j;
    float s = 0.f;
#pragma unroll 4
    for (int d = 0; d < 512; ++d)
        s += col[half * 512 + d] * vp[(size_t)d * NVEC];
    part[t] = s;
    __syncthreads();
    if (t < 128) G0[i * NVEC + t] = part[t] + part[t + 128];
}

// ---------------------------------------------------------------------------
// K2: T = R^{-1}, R = 0.5*I + strict_upper(G), G = G0 * rn_i * rn_j
// ---------------------------------------------------------------------------
__global__ __launch_bounds__(256) void k_tinv(const float* __restrict__ G0,
                                              const float* __restrict__ rn,
                                              float* __restrict__ Tout) {
    __shared__ __align__(16) float Ts[NVEC * NVEC];   // 65536 B
    __shared__ float rs[NVEC];
    int t = threadIdx.x;
    if (t < NVEC) rs[t] = rn[t];
    __syncthreads();

    {   // phase 0: R into LDS (0.5 on diag, zeros below), rn rescale folded
        int i = t >> 1, jb = (t & 1) * 64;
        float rni = rs[i];
        for (int j = jb; j < jb + 64; j++) {
            float val = 0.f;
            if (j > i)       val = G0[i * NVEC + j] * rni * rs[j];
            else if (j == i) val = 0.5f;
            Ts[i * NVEC + j] = val;
        }
    }
    __syncthreads();

    {   // phase 1: invert 8 diagonal 16x16 blocks
        int blk = t >> 4, c = t & 15, rb = blk * 16;
        float xs[16];
        if (t < 128) {
#pragma unroll
            for (int jj = 0; jj < 16; jj++) xs[jj] = (jj == c) ? 2.f : 0.f;
#pragma unroll
            for (int i = 14; i >= 0; i--) {
                float s = 0.f;
#pragma unroll
                for (int j = i + 1; j < 16; j++)
                    s += Ts[(rb + i) * NVEC + rb + j] * xs[j];
                if (i < c) xs[i] = -2.f * s;
            }
        }
        __syncthreads();
        if (t < 128) {
#pragma unroll
            for (int i = 0; i < 16; i++)
                if (i <= c) Ts[(rb + i) * NVEC + rb + c] = xs[i];
        }
        __syncthreads();
    }

    // phase 2: combine levels
#pragma unroll
    for (int L = 16; L <= 64; L <<= 1) {
        int tpp = L << 2;
        int p   = t / tpp;
        int rem = t % tpp;
        int r   = rem / (L >> 2);
        int c0  = (rem % (L >> 2)) << 2;
        int a0  = p * (L << 1), b0 = a0 + L;
        int npanel = L >> 4;
        for (int pi = 0; pi < npanel; pi++) {
            int gr = a0 + pi * 16 + r;
            f32x4 acc = {0.f, 0.f, 0.f, 0.f};
            for (int k = pi * 16 + r; k < L; k++)
                acc += Ts[gr * NVEC + a0 + k] *
                       *(const f32x4*)&Ts[(a0 + k) * NVEC + b0 + c0];
            *(f32x4*)&Ts[(64 + r) * NVEC + p * L + c0] = acc;
            __syncthreads();
            f32x4 acc2 = {0.f, 0.f, 0.f, 0.f};
            for (int k = 0; k <= c0 + 3; k++)
                acc2 += Ts[(64 + r) * NVEC + p * L + k] *
                        *(const f32x4*)&Ts[(b0 + k) * NVEC + b0 + c0];
            *(f32x4*)&Ts[gr * NVEC + b0 + c0] = -acc2;
            __syncthreads();
        }
    }

    for (int idx = t; idx < NVEC * NVEC; idx += 256) {
        int i = idx >> 7, j = idx & 127;
        Tout[idx] = (j >= i) ? Ts[idx] : 0.f;
    }
}

// ---------------------------------------------------------------------------
// K3: W[d][i] = sum_j Vn[d][j] * T[i][j]   (T has explicit zeros below diag)
// ---------------------------------------------------------------------------
__global__ __launch_bounds__(256) void k_wmat(const float* __restrict__ VnT,
                                              const float* __restrict__ T,
                                              unsigned short* __restrict__ W16) {
    __shared__ float Tl[NVEC * 130];
    int t = threadIdx.x;
#pragma unroll
    for (int m = 0; m < 32; ++m) {
        int idx = t * 2 + m * 512;
        float2 f = *(const float2*)(T + idx);
        int r = idx >> 7, c = idx & 127;
        *(float2*)&Tl[r * 130 + c] = f;
    }
    __syncthreads();
    int dl = t & 7, ig = t >> 3;
    int d  = blockIdx.x * 8 + dl;
    int i0 = ig * 4;
    float a0 = 0.f, a1 = 0.f, a2 = 0.f, a3 = 0.f;
#pragma unroll 4
    for (int j = 0; j < NVEC; ++j) {
        float vn = VnT[(size_t)j * DIM + d];
        a0 += vn * Tl[(i0 + 0) * 130 + j];
        a1 += vn * Tl[(i0 + 1) * 130 + j];
        a2 += vn * Tl[(i0 + 2) * 130 + j];
        a3 += vn * Tl[(i0 + 3) * 130 + j];
    }
    ushort4 h; h.x = f2bf(a0); h.y = f2bf(a1); h.z = f2bf(a2); h.w = f2bf(a3);
    *(ushort4*)(W16 + (size_t)d * NVEC + i0) = h;
}

// ---------------------------------------------------------------------------
// K4 (fused, near-barrier-free): 512 blocks x 512 threads (8 waves, 2/CU).
// Insight: Vn16 (256KB) and W16 (256KB) are L2-resident per XCD; x's MFMA
// A-fragment is 8 contiguous fp32 per lane. So NO LDS staging for A or B:
//   phase A: Y = x @ Vn -- A loaded per-lane from x (fp32->bf16 in regs,
//            same f2bf points as before), B loaded per-lane from VnT16 (L2).
//   handoff: Y -> LDS (swizzled), ONE __syncthreads in the whole kernel.
//   phase B: out = x - Y @ W^T + b -- Y A-frags hoisted to 16 VGPRs (ct-
//            invariant), W B-frags per-lane from L2, epilogue x re-read L2-hit.
// No barrier-drain points => compiler + 16 waves/CU TLP hide HBM latency.
// out stores nontemporal (write-once; keeps L2 clean for Vn/W/x).
// LDS = 16KB (Ys only). MFMA order identical to round 3 => absmax identical.
// ---------------------------------------------------------------------------
__global__ __launch_bounds__(512, 4) void k_fused(const float* __restrict__ x,
                                                  const unsigned short* __restrict__ VnT16,
                                                  const unsigned short* __restrict__ W16,
                                                  const float* __restrict__ bias,
                                                  float* __restrict__ out) {
    __shared__ __align__(16) char Ysb[64 * 256];     // 16 KB, swizzled rows

    const int t  = threadIdx.x;
    const int r0 = blockIdx.x * 64;
    const int w  = t >> 6, l = t & 63, q = l >> 4, lm = l & 15;
    const int wm = w & 3, wn = w >> 2;               // wave tile: rows wm*16, cols wn*64

    // A-operand: lane (q,lm) covers x[r0+wm*16+lm][k0+kk+q*8 .. +7]
    const float* xa = x + (size_t)(r0 + wm * 16 + lm) * DIM + q * 8;
    // B-operand: lane (q,lm), nt: VnT16[wn*64+nt*16+lm][k0+kk+q*8 .. +7]
    const unsigned short* vb = VnT16 + (size_t)(wn * 64 + lm) * DIM + q * 8;

    // ---------------- phase A: Y = x @ Vn ----------------
    f32x4 acc[4];
#pragma unroll
    for (int n = 0; n < 4; ++n) acc[n] = (f32x4){0.f, 0.f, 0.f, 0.f};

#pragma unroll 1
    for (int s = 0; s < 8; ++s) {
        const int k0 = s * 128;
#pragma unroll
        for (int kk = 0; kk < 128; kk += 32) {
            float4 a0 = *(const float4*)(xa + k0 + kk);
            float4 a1 = *(const float4*)(xa + k0 + kk + 4);
            s16x8 a;
            a[0] = (short)f2bf(a0.x); a[1] = (short)f2bf(a0.y);
            a[2] = (short)f2bf(a0.z); a[3] = (short)f2bf(a0.w);
            a[4] = (short)f2bf(a1.x); a[5] = (short)f2bf(a1.y);
            a[6] = (short)f2bf(a1.z); a[7] = (short)f2bf(a1.w);
#pragma unroll
            for (int nt = 0; nt < 4; ++nt) {
                s16x8 b = *(const s16x8*)(vb + (size_t)(nt * 16) * DIM + k0 + kk);
                acc[nt] = __builtin_amdgcn_mfma_f32_16x16x32_bf16(a, b, acc[nt], 0, 0, 0);
            }
        }
    }

    // Y (bf16) -> LDS, swizzled. C/D layout: col=lane&15, row=q*4+reg.
    {
        int yr0 = wm * 16 + q * 4;
#pragma unroll
        for (int nt = 0; nt < 4; ++nt) {
            int col2 = (wn * 64 + nt * 16 + lm) * 2;
#pragma unroll
            for (int r = 0; r < 4; ++r) {
                int row = yr0 + r;
                *(unsigned short*)(Ysb + row * 256 + (col2 ^ ((row & 15) << 4)))
                    = f2bf(acc[nt][r]);
            }
        }
    }
    __syncthreads();                                 // the ONLY barrier

    // ---------------- phase B: out = x - Y @ W^T + b ----------------
    // Y A-frags are ct-invariant: hoist to registers (16 VGPR).
    const int arow = (wm * 16 + lm) * 256;
    const int ms   = lm << 4;
    s16x8 ya[4];
#pragma unroll
    for (int kk = 0; kk < 4; ++kk)
        ya[kk] = *(const s16x8*)(Ysb + arow + (((kk * 32 + q * 8) * 2) ^ ms));

    const unsigned short* wb = W16 + (size_t)(wn * 64 + lm) * NVEC + q * 8;
    const int orow = r0 + wm * 16 + q * 4;

#pragma unroll 1
    for (int ct = 0; ct < 8; ++ct) {
        const unsigned short* wct = wb + (size_t)(ct * 128) * NVEC;
        f32x4 oacc[4];
#pragma unroll
        for (int n = 0; n < 4; ++n) oacc[n] = (f32x4){0.f, 0.f, 0.f, 0.f};
#pragma unroll
        for (int kk = 0; kk < 4; ++kk) {
#pragma unroll
            for (int nt = 0; nt < 4; ++nt) {
                s16x8 b = *(const s16x8*)(wct + (size_t)(nt * 16) * NVEC + kk * 32);
                oacc[nt] = __builtin_amdgcn_mfma_f32_16x16x32_bf16(ya[kk], b, oacc[nt], 0, 0, 0);
            }
        }
        // epilogue: out = x - acc + b (x re-read L2-hit; out nontemporal)
#pragma unroll
        for (int nt = 0; nt < 4; ++nt) {
            int col = ct * 128 + wn * 64 + nt * 16 + lm;
            float bv = bias[col];
#pragma unroll
            for (int r = 0; r < 4; ++r) {
                size_t idx = (size_t)(orow + r) * DIM + col;
                __builtin_nontemporal_store(x[idx] - oacc[nt][r] + bv, &out[idx]);
            }
        }
    }
}

// ---------------------------------------------------------------------------
extern "C" void kernel_launch(void* const* d_in, const int* in_sizes, int n_in,
                              void* d_out, int out_size, void* d_ws, size_t ws_size,
                              hipStream_t stream) {
    const float* x    = (const float*)d_in[0];
    const float* v    = (const float*)d_in[1];
    const float* bias = (const float*)d_in[2];
    float* out = (float*)d_out;

    char* ws = (char*)d_ws;
    float*          VnT   = (float*)(ws);                    // 512 KB  [NVEC][DIM] fp32
    unsigned short* VnT16 = (unsigned short*)(ws + 524288);  // 256 KB  [NVEC][DIM] bf16
    float*          G0    = (float*)(ws + 786432);           // 64 KB   raw Gram
    float*          T     = (float*)(ws + 851968);           // 64 KB
    float*          rn    = (float*)(ws + 917504);           // 512 B   col inv-norms
    unsigned short* W16   = (unsigned short*)(ws + 921600);  // 256 KB  [DIM][NVEC] bf16

    k_normgram<<<NVEC, 256, 0, stream>>>(v, VnT, VnT16, rn, G0);
    k_tinv<<<1, 256, 0, stream>>>(G0, rn, T);
    k_wmat<<<DIM / 8, 256, 0, stream>>>(VnT, T, W16);
    k_fused<<<BROWS / 64, 512, 0, stream>>>(x, VnT16, W16, bias, out);
}

// Round 6
// 349.608 us; speedup vs baseline: 1.1550x; 1.1550x over previous
//
#include <hip/hip_runtime.h>
#include <hip/hip_bf16.h>

#define DIM   1024
#define NVEC  128
#define BROWS 32768

typedef short s16x8 __attribute__((ext_vector_type(8)));
typedef float f32x4 __attribute__((ext_vector_type(4)));

__device__ __forceinline__ unsigned short f2bf(float f) {
    union { float f; unsigned int u; } c; c.f = f;
    unsigned int u = c.u;
    u += 0x7fffu + ((u >> 16) & 1u);   // round-to-nearest-even
    return (unsigned short)(u >> 16);
}

// async global->LDS, 16B per lane; LDS dest = wave-uniform base + lane*16
__device__ __forceinline__ void cp16(const void* g, void* l) {
    __builtin_amdgcn_global_load_lds(
        (const __attribute__((address_space(1))) unsigned int*)g,
        (__attribute__((address_space(3))) unsigned int*)l, 16, 0, 0);
}

// ---------------------------------------------------------------------------
// K1: per-column normalize v AND raw Gram row (rescale trick):
//   G[i][j] = <v_i_raw, v_j_raw> * rn_i * rn_j  (scaling applied in k_tinv)
// ---------------------------------------------------------------------------
__global__ __launch_bounds__(256) void k_normgram(const float* __restrict__ v,
                                                  float* __restrict__ VnT,
                                                  unsigned short* __restrict__ VnT16,
                                                  float* __restrict__ rn_out,
                                                  float* __restrict__ G0) {
    int i = blockIdx.x, t = threadIdx.x;
    __shared__ float col[DIM];
    __shared__ float red[4];
    __shared__ float part[256];
    float c4[4]; float ss = 0.f;
#pragma unroll
    for (int u = 0; u < 4; ++u) {
        int d = t + u * 256;
        float val = v[d * NVEC + i];
        c4[u] = val; col[d] = val; ss += val * val;
    }
#pragma unroll
    for (int o = 32; o > 0; o >>= 1) ss += __shfl_down(ss, o, 64);
    if ((t & 63) == 0) red[t >> 6] = ss;
    __syncthreads();
    float rn = rsqrtf(red[0] + red[1] + red[2] + red[3]);
    if (t == 0) rn_out[i] = rn;
#pragma unroll
    for (int u = 0; u < 4; ++u) {
        int d = t + u * 256;
        float val = c4[u] * rn;
        VnT[i * DIM + d]   = val;
        VnT16[i * DIM + d] = f2bf(val);
    }
    // raw Gram row: thread t -> j = t&127, d-half = t>>7
    int j = t & 127, half = t >> 7;
    const float* vp = v + (size_t)(half * 512) * NVEC + j;
    float s = 0.f;
#pragma unroll 4
    for (int d = 0; d < 512; ++d)
        s += col[half * 512 + d] * vp[(size_t)d * NVEC];
    part[t] = s;
    __syncthreads();
    if (t < 128) G0[i * NVEC + t] = part[t] + part[t + 128];
}

// ---------------------------------------------------------------------------
// K2: T = R^{-1}, R = 0.5*I + strict_upper(G), G = G0 * rn_i * rn_j
// ---------------------------------------------------------------------------
__global__ __launch_bounds__(256) void k_tinv(const float* __restrict__ G0,
                                              const float* __restrict__ rn,
                                              float* __restrict__ Tout) {
    __shared__ __align__(16) float Ts[NVEC * NVEC];   // 65536 B
    __shared__ float rs[NVEC];
    int t = threadIdx.x;
    if (t < NVEC) rs[t] = rn[t];
    __syncthreads();

    {   // phase 0: R into LDS (0.5 on diag, zeros below), rn rescale folded
        int i = t >> 1, jb = (t & 1) * 64;
        float rni = rs[i];
        for (int j = jb; j < jb + 64; j++) {
            float val = 0.f;
            if (j > i)       val = G0[i * NVEC + j] * rni * rs[j];
            else if (j == i) val = 0.5f;
            Ts[i * NVEC + j] = val;
        }
    }
    __syncthreads();

    {   // phase 1: invert 8 diagonal 16x16 blocks
        int blk = t >> 4, c = t & 15, rb = blk * 16;
        float xs[16];
        if (t < 128) {
#pragma unroll
            for (int jj = 0; jj < 16; jj++) xs[jj] = (jj == c) ? 2.f : 0.f;
#pragma unroll
            for (int i = 14; i >= 0; i--) {
                float s = 0.f;
#pragma unroll
                for (int j = i + 1; j < 16; j++)
                    s += Ts[(rb + i) * NVEC + rb + j] * xs[j];
                if (i < c) xs[i] = -2.f * s;
            }
        }
        __syncthreads();
        if (t < 128) {
#pragma unroll
            for (int i = 0; i < 16; i++)
                if (i <= c) Ts[(rb + i) * NVEC + rb + c] = xs[i];
        }
        __syncthreads();
    }

    // phase 2: combine levels
#pragma unroll
    for (int L = 16; L <= 64; L <<= 1) {
        int tpp = L << 2;
        int p   = t / tpp;
        int rem = t % tpp;
        int r   = rem / (L >> 2);
        int c0  = (rem % (L >> 2)) << 2;
        int a0  = p * (L << 1), b0 = a0 + L;
        int npanel = L >> 4;
        for (int pi = 0; pi < npanel; pi++) {
            int gr = a0 + pi * 16 + r;
            f32x4 acc = {0.f, 0.f, 0.f, 0.f};
            for (int k = pi * 16 + r; k < L; k++)
                acc += Ts[gr * NVEC + a0 + k] *
                       *(const f32x4*)&Ts[(a0 + k) * NVEC + b0 + c0];
            *(f32x4*)&Ts[(64 + r) * NVEC + p * L + c0] = acc;
            __syncthreads();
            f32x4 acc2 = {0.f, 0.f, 0.f, 0.f};
            for (int k = 0; k <= c0 + 3; k++)
                acc2 += Ts[(64 + r) * NVEC + p * L + k] *
                        *(const f32x4*)&Ts[(b0 + k) * NVEC + b0 + c0];
            *(f32x4*)&Ts[gr * NVEC + b0 + c0] = -acc2;
            __syncthreads();
        }
    }

    for (int idx = t; idx < NVEC * NVEC; idx += 256) {
        int i = idx >> 7, j = idx & 127;
        Tout[idx] = (j >= i) ? Ts[idx] : 0.f;
    }
}

// ---------------------------------------------------------------------------
// K3: W[d][i] = sum_j Vn[d][j] * T[i][j]   (T has explicit zeros below diag)
// ---------------------------------------------------------------------------
__global__ __launch_bounds__(256) void k_wmat(const float* __restrict__ VnT,
                                              const float* __restrict__ T,
                                              unsigned short* __restrict__ W16) {
    __shared__ float Tl[NVEC * 130];
    int t = threadIdx.x;
#pragma unroll
    for (int m = 0; m < 32; ++m) {
        int idx = t * 2 + m * 512;
        float2 f = *(const float2*)(T + idx);
        int r = idx >> 7, c = idx & 127;
        *(float2*)&Tl[r * 130 + c] = f;
    }
    __syncthreads();
    int dl = t & 7, ig = t >> 3;
    int d  = blockIdx.x * 8 + dl;
    int i0 = ig * 4;
    float a0 = 0.f, a1 = 0.f, a2 = 0.f, a3 = 0.f;
#pragma unroll 4
    for (int j = 0; j < NVEC; ++j) {
        float vn = VnT[(size_t)j * DIM + d];
        a0 += vn * Tl[(i0 + 0) * 130 + j];
        a1 += vn * Tl[(i0 + 1) * 130 + j];
        a2 += vn * Tl[(i0 + 2) * 130 + j];
        a3 += vn * Tl[(i0 + 3) * 130 + j];
    }
    ushort4 h; h.x = f2bf(a0); h.y = f2bf(a1); h.z = f2bf(a2); h.w = f2bf(a3);
    *(ushort4*)(W16 + (size_t)d * NVEC + i0) = h;
}

// ---------------------------------------------------------------------------
// K4 (fused, stage-ahead dbuf): 512 blocks x 512 threads (8 waves, 2/CU).
// Round-5 lesson: per-lane 16B B/W loads = 64 cache lines/instr -> L2
// request-rate bound (1.79 TB/s). Round-3 lesson: stage-then-barrier
// exposes full staging latency each step. Fix: coalesced global_load_lds
// staging (round 3) + DOUBLE BUFFER with next-tile stage issued BEFORE
// current-tile MFMA -> the step-ending __syncthreads (vmcnt(0) drain)
// lands after the loads had the whole MFMA to fly.
//   phase A: Y = x @ Vn. x per-lane -> regs, 2-deep named buffers (xfA/xfB,
//            static idx), prefetched 1 step ahead. Vn tile cp16 -> Bs dbuf.
//   handoff: Y -> LDS swizzled (1 barrier).
//   phase B: out = x - Y @ W^T + b. ya hoisted (ct-invariant, 16 VGPR);
//            W tile cp16 -> Ws dbuf, stage-ahead. Plain stores (NT caused
//            +43MB write amplification in round 5).
// LDS 80KB aliased: phaseA Bs0|Bs1 = 0..64K; phaseB Ys 0..16K, Ws0 16..48K,
// Ws1 48..80K. All buffer transitions barrier-separated. Swizzle layouts
// identical to rounds 3/5 (both passed). MFMA order identical -> same absmax.
// ---------------------------------------------------------------------------
__global__ __launch_bounds__(512, 4) void k_fused(const float* __restrict__ x,
                                                  const unsigned short* __restrict__ VnT16,
                                                  const unsigned short* __restrict__ W16,
                                                  const float* __restrict__ bias,
                                                  float* __restrict__ out) {
    __shared__ __align__(16) char smem[81920];       // 80 KB
    char* Bs0 = smem;                                // [128][256B] 32KB (phase A)
    char* Bs1 = smem + 32768;                        // [128][256B] 32KB (phase A)
    char* Ysb = smem;                                // [64][256B]  16KB (phase B)
    char* Ws0 = smem + 16384;                        // [128][256B] 32KB (phase B)
    char* Ws1 = smem + 49152;                        // [128][256B] 32KB (phase B)

    const int t  = threadIdx.x;
    const int r0 = blockIdx.x * 64;
    const int w  = t >> 6, l = t & 63, q = l >> 4, lm = l & 15;
    const int wm = w & 3, wn = w >> 2;               // wave tile: rows wm*16, cols wn*64
    const int lr = l >> 4, lc = l & 15;              // gload lane -> (row, 16B-chunk)
    const int ms = lm << 4;

    // A-operand: lane (q,lm) covers x[r0+wm*16+lm][k0 + kk + q*8 .. +7]
    const float* xa = x + (size_t)(r0 + wm * 16 + lm) * DIM + q * 8;

    float4 xfA[8], xfB[8];

#define LDXF(XF, K0) { _Pragma("unroll") for (int k4_ = 0; k4_ < 4; ++k4_) {    \
        XF[2 * k4_]     = *(const float4*)(xa + (K0) + k4_ * 32);               \
        XF[2 * k4_ + 1] = *(const float4*)(xa + (K0) + k4_ * 32 + 4); } }

#define GLB(BSB, K0) { _Pragma("unroll") for (int j_ = 0; j_ < 4; ++j_) {       \
        int row_ = w * 16 + j_ * 4 + lr;                                        \
        cp16(VnT16 + (size_t)row_ * DIM + (K0) + ((lc ^ (row_ & 15)) << 3),     \
             (BSB) + (w * 16 + j_ * 4) * 256); } }

#define GLW(WSB, CT) { _Pragma("unroll") for (int j_ = 0; j_ < 4; ++j_) {       \
        int row_ = w * 16 + j_ * 4 + lr;                                        \
        cp16(W16 + (size_t)((CT) * 128 + row_) * NVEC + ((lc ^ (row_ & 15)) << 3), \
             (WSB) + (w * 16 + j_ * 4) * 256); } }

#define MMA_A(XF, BSB) { _Pragma("unroll") for (int k4_ = 0; k4_ < 4; ++k4_) {  \
        s16x8 a_;                                                               \
        a_[0] = (short)f2bf(XF[2*k4_].x);   a_[1] = (short)f2bf(XF[2*k4_].y);   \
        a_[2] = (short)f2bf(XF[2*k4_].z);   a_[3] = (short)f2bf(XF[2*k4_].w);   \
        a_[4] = (short)f2bf(XF[2*k4_+1].x); a_[5] = (short)f2bf(XF[2*k4_+1].y); \
        a_[6] = (short)f2bf(XF[2*k4_+1].z); a_[7] = (short)f2bf(XF[2*k4_+1].w); \
        _Pragma("unroll") for (int nt_ = 0; nt_ < 4; ++nt_) {                   \
            s16x8 b_ = *(const s16x8*)((BSB) + (wn * 64 + nt_ * 16 + lm) * 256  \
                                            + (((k4_ * 32 + q * 8) * 2) ^ ms)); \
            acc[nt_] = __builtin_amdgcn_mfma_f32_16x16x32_bf16(a_, b_, acc[nt_], 0, 0, 0); } } }

    // ---------------- phase A: Y = x @ Vn ----------------
    f32x4 acc[4];
#pragma unroll
    for (int n = 0; n < 4; ++n) acc[n] = (f32x4){0.f, 0.f, 0.f, 0.f};

    LDXF(xfA, 0);
    GLB(Bs0, 0);
    __syncthreads();                                 // initial stage drain (once)

#pragma unroll 1
    for (int p = 0; p < 4; ++p) {
        // step 2p: compute Bs0/xfA; prefetch step 2p+1 first
        LDXF(xfB, (2 * p + 1) * 128);
        GLB(Bs1, (2 * p + 1) * 128);                 // Bs1 last read step 2p-1 (barrier passed)
        MMA_A(xfA, Bs0);
        __syncthreads();                             // drains Bs1 stage + xfB loads
        // step 2p+1: compute Bs1/xfB; prefetch step 2p+2
        if (p < 3) {
            LDXF(xfA, (2 * p + 2) * 128);
            GLB(Bs0, (2 * p + 2) * 128);
        }
        MMA_A(xfB, Bs1);
        __syncthreads();
    }

    // Y (bf16) -> LDS, swizzled. C/D layout: col=lane&15, row=q*4+reg.
    {
        int yr0 = wm * 16 + q * 4;
#pragma unroll
        for (int nt = 0; nt < 4; ++nt) {
            int col2 = (wn * 64 + nt * 16 + lm) * 2;
#pragma unroll
            for (int r = 0; r < 4; ++r) {
                int row = yr0 + r;
                *(unsigned short*)(Ysb + row * 256 + (col2 ^ ((row & 15) << 4)))
                    = f2bf(acc[nt][r]);
            }
        }
    }
    __syncthreads();                                 // Ys visible to all waves

    // ---------------- phase B: out = x - Y @ W^T + b ----------------
    // Y A-frags are ct-invariant: hoist to registers (16 VGPR).
    const int arow = (wm * 16 + lm) * 256;
    s16x8 ya[4];
#pragma unroll
    for (int kk = 0; kk < 4; ++kk)
        ya[kk] = *(const s16x8*)(Ysb + arow + (((kk * 32 + q * 8) * 2) ^ ms));

    const int orow = r0 + wm * 16 + q * 4;

#define MMA_B_EPI(WSB, CT) {                                                    \
        f32x4 oacc[4];                                                          \
        _Pragma("unroll") for (int n_ = 0; n_ < 4; ++n_)                        \
            oacc[n_] = (f32x4){0.f, 0.f, 0.f, 0.f};                             \
        _Pragma("unroll") for (int k4_ = 0; k4_ < 4; ++k4_) {                   \
            _Pragma("unroll") for (int nt_ = 0; nt_ < 4; ++nt_) {               \
                s16x8 b_ = *(const s16x8*)((WSB) + (wn * 64 + nt_ * 16 + lm) * 256 \
                                                + (((k4_ * 32 + q * 8) * 2) ^ ms)); \
                oacc[nt_] = __builtin_amdgcn_mfma_f32_16x16x32_bf16(ya[k4_], b_, oacc[nt_], 0, 0, 0); } } \
        _Pragma("unroll") for (int nt_ = 0; nt_ < 4; ++nt_) {                   \
            int col_ = (CT) * 128 + wn * 64 + nt_ * 16 + lm;                    \
            float bv_ = bias[col_];                                             \
            _Pragma("unroll") for (int r_ = 0; r_ < 4; ++r_) {                  \
                size_t idx_ = (size_t)(orow + r_) * DIM + col_;                 \
                out[idx_] = x[idx_] - oacc[nt_][r_] + bv_; } } }

    GLW(Ws0, 0);                                     // Ws0 disjoint from Ysb (ya reads)
    __syncthreads();                                 // initial W stage drain

#pragma unroll 1
    for (int pc = 0; pc < 4; ++pc) {
        GLW(Ws1, 2 * pc + 1);                        // Ws1 last read step 2pc-1 (barrier passed)
        MMA_B_EPI(Ws0, 2 * pc);
        __syncthreads();
        if (pc < 3) GLW(Ws0, 2 * pc + 2);
        MMA_B_EPI(Ws1, 2 * pc + 1);
        __syncthreads();
    }
#undef LDXF
#undef GLB
#undef GLW
#undef MMA_A
#undef MMA_B_EPI
}

// ---------------------------------------------------------------------------
extern "C" void kernel_launch(void* const* d_in, const int* in_sizes, int n_in,
                              void* d_out, int out_size, void* d_ws, size_t ws_size,
                              hipStream_t stream) {
    const float* x    = (const float*)d_in[0];
    const float* v    = (const float*)d_in[1];
    const float* bias = (const float*)d_in[2];
    float* out = (float*)d_out;

    char* ws = (char*)d_ws;
    float*          VnT   = (float*)(ws);                    // 512 KB  [NVEC][DIM] fp32
    unsigned short* VnT16 = (unsigned short*)(ws + 524288);  // 256 KB  [NVEC][DIM] bf16
    float*          G0    = (float*)(ws + 786432);           // 64 KB   raw Gram
    float*          T     = (float*)(ws + 851968);           // 64 KB
    float*          rn    = (float*)(ws + 917504);           // 512 B   col inv-norms
    unsigned short* W16   = (unsigned short*)(ws + 921600);  // 256 KB  [DIM][NVEC] bf16

    k_normgram<<<NVEC, 256, 0, stream>>>(v, VnT, VnT16, rn, G0);
    k_tinv<<<1, 256, 0, stream>>>(G0, rn, T);
    k_wmat<<<DIM / 8, 256, 0, stream>>>(VnT, T, W16);
    k_fused<<<BROWS / 64, 512, 0, stream>>>(x, VnT16, W16, bias, out);
}